// Round 9
// baseline (367.625 us; speedup 1.0000x reference)
//
#include <hip/hip_runtime.h>
#include <cstdint>
#include <cstddef>

typedef unsigned short ushort_t;
typedef unsigned int uint_t;

typedef __bf16 bf16x8 __attribute__((ext_vector_type(8)));
typedef float floatx4 __attribute__((ext_vector_type(4)));

#define B_ 16
#define N1_ 4096
#define N2_ 1024
#define C1_ 128
#define C2_ 256
#define DIN_ 384
#define DOUT_ 256
#define M_ (B_ * N1_)  // 65536

// ---------------- helpers ----------------

__device__ __forceinline__ ushort_t f2bf(float f) {
  unsigned int u = __builtin_bit_cast(unsigned int, f);
  u = (u + 0x7fffu + ((u >> 16) & 1u)) >> 16;  // RNE
  return (ushort_t)u;
}

// ---------------- kernel P: weight swizzle + bf16 convert ----------------
// W1s[t][n][kk] = bf16(W1[t*32+kk][n]), t=0..11, n=0..255, kk=0..31

__global__ __launch_bounds__(256) void prep_kernel(
    const float* __restrict__ W1, const float* __restrict__ W2,
    ushort_t* __restrict__ W1s, ushort_t* __restrict__ W2s) {
  int e = blockIdx.x * 256 + threadIdx.x;
  if (e < DOUT_ * DIN_) {  // 98304
    int kk = e & 31, n = (e >> 5) & 255, t = e >> 13;
    W1s[e] = f2bf(W1[(size_t)(t * 32 + kk) * DOUT_ + n]);
  }
  if (e < DOUT_ * DOUT_) {  // 65536
    int kk = e & 31, n = (e >> 5) & 255, t = e >> 13;
    W2s[e] = f2bf(W2[(size_t)(t * 32 + kk) * DOUT_ + n]);
  }
}

// ---------------- knn primitives (verbatim from verified kernel) ----------

__device__ __forceinline__ void ins_exact(float& s0, float& s1, float& s2,
                                          int& i0, int& i1, int& i2,
                                          float d, int p) {
  float ns2 = __builtin_amdgcn_fmed3f(d, s1, s2);
  float ns1 = __builtin_amdgcn_fmed3f(d, s0, s1);
  float ns0 = fminf(d, s0);
  bool c0 = d < s0, c1 = d < s1, c2 = d < s2;
  i2 = c1 ? i1 : (c2 ? p : i2);
  i1 = c0 ? i0 : (c1 ? p : i1);
  i0 = c0 ? p : i0;
  s0 = ns0; s1 = ns1; s2 = ns2;
}

__device__ __forceinline__ void ins_merge(float& s0, float& s1, float& s2,
                                          int& i0, int& i1, int& i2,
                                          float e, int j) {
  bool t0 = (e < s0) || (e == s0 && j < i0);
  bool t1 = (e < s1) || (e == s1 && j < i1);
  bool t2 = (e < s2) || (e == s2 && j < i2);
  s2 = t1 ? s1 : (t2 ? e : s2);
  i2 = t1 ? i1 : (t2 ? j : i2);
  s1 = t0 ? s0 : (t1 ? e : s1);
  i1 = t0 ? i0 : (t1 ? j : i1);
  s0 = t0 ? e : s0;
  i0 = t0 ? j : i0;
}

// ---------------- fully fused, software-pipelined ----------------
// 64 rows/block as TWO 32-row subtiles, 1024 blocks, 256 threads (4 waves).
// knn(tile0) = prologue (verified 32-row geometry). knn(tile1)'s 128
// candidates/thread are interleaved IN-STREAM into GEMM1/2(tile0): 6
// candidates after each MFMA quad (20 t-steps x 6 = 120, +8 leftover).
// Same scan order p = sub + 8t -> byte-identical semantics. The scheduler
// fills MFMA/W-load/ds_read latency with knn VALU ops from the SAME wave
// (R8 showed block-level drift alone leaves knn ~28 us exposed: in-order
// issue within a phase can't cross-hide).
// LDS: xs4 16 KB dedicated (live through GEMM(0)) + As 24 KB (32-row tile,
// HS aliases front 16 KB) + idx/w 0.75 KB = ~41 KB -> 3 blocks/CU.

__global__ __launch_bounds__(256, 2) void fused_kernel(
    const float* __restrict__ xyz1, const float* __restrict__ xyz2,
    const float* __restrict__ feat1, const float* __restrict__ feat2,
    const ushort_t* __restrict__ W1s, const float* __restrict__ b1,
    const ushort_t* __restrict__ W2s, const float* __restrict__ b2,
    float* __restrict__ out) {
  __shared__ __align__(16) float4 xs4[N2_];        // 16 KB, live whole block
  __shared__ __align__(16) ushort_t As[32 * 384];  // 24 KB; HS aliases front
  __shared__ int idxL[32 * 3];
  __shared__ float wL[32 * 3];

  const int tid = threadIdx.x;
  const int wave = tid >> 6;
  const int lane = tid & 63;
  const int m = lane & 15;
  const int q = lane >> 4;
  const int row0 = blockIdx.x * 64;
  const int b = row0 >> 12;

  // ---- stage xyz2 batch slice into dedicated xs4 ----
  {
    const float4* p24 = (const float4*)(xyz2 + (size_t)b * (N2_ * 3));
    float4 A = p24[3 * tid + 0];
    float4 Bv = p24[3 * tid + 1];
    float4 Cv = p24[3 * tid + 2];
    xs4[4 * tid + 0] = make_float4(A.x, A.y, A.z, 0.0f);
    xs4[4 * tid + 1] = make_float4(A.w, Bv.x, Bv.y, 0.0f);
    xs4[4 * tid + 2] = make_float4(Bv.z, Bv.w, Cv.x, 0.0f);
    xs4[4 * tid + 3] = make_float4(Cv.y, Cv.z, Cv.w, 0.0f);
  }
  __syncthreads();

  const int gk = tid >> 3;   // 0..31 (row within subtile)
  const int subk = tid & 7;  // candidate sub-slice

  // ---- knn(tile0): verified 32-row geometry, full scan ----
  {
    const int row = row0 + gk;
    const float* p1 = xyz1 + (size_t)row * 3;
    float x1 = p1[0], y1 = p1[1], z1 = p1[2];
    float s0 = 3.0e38f, s1 = 3.0e38f, s2 = 3.0e38f;
    int i0 = 0, i1 = 0, i2 = 0;
    int p = subk;
#pragma unroll 8
    for (int t = 0; t < N2_ / 8; ++t) {
      float4 qv = xs4[p];
      float dx = x1 - qv.x, dy = y1 - qv.y, dz = z1 - qv.z;
      float d = dx * dx + dy * dy + dz * dz;
      ins_exact(s0, s1, s2, i0, i1, i2, d, p);
      p += 8;
    }
#pragma unroll
    for (int mm = 1; mm <= 4; mm <<= 1) {
      float e0 = __shfl_xor(s0, mm), e1 = __shfl_xor(s1, mm), e2 = __shfl_xor(s2, mm);
      int j0 = __shfl_xor(i0, mm), j1 = __shfl_xor(i1, mm), j2 = __shfl_xor(i2, mm);
      ins_merge(s0, s1, s2, i0, i1, i2, e0, j0);
      ins_merge(s0, s1, s2, i0, i1, i2, e1, j1);
      ins_merge(s0, s1, s2, i0, i1, i2, e2, j2);
    }
    if (subk == 0) {
      float r0 = 1.0f / fmaxf(s0, 1e-10f);
      float r1 = 1.0f / fmaxf(s1, 1e-10f);
      float r2 = 1.0f / fmaxf(s2, 1e-10f);
      float s = 1.0f / (r0 + r1 + r2);
      idxL[gk * 3 + 0] = i0; idxL[gk * 3 + 1] = i1; idxL[gk * 3 + 2] = i2;
      wL[gk * 3 + 0] = r0 * s; wL[gk * 3 + 1] = r1 * s; wL[gk * 3 + 2] = r2 * s;
    }
  }
  __syncthreads();

  // ---- knn(tile1) persistent state (scan interleaved into GEMM below) ----
  float kx, ky, kz;
  float ks0 = 3.0e38f, ks1 = 3.0e38f, ks2 = 3.0e38f;
  int ki0 = 0, ki1 = 0, ki2 = 0;
  int pk = subk;
  {
    const float* p1 = xyz1 + (size_t)(row0 + 32 + gk) * 3;
    kx = p1[0]; ky = p1[1]; kz = p1[2];
  }

#define KNN_CHUNK(N)                                                \
  _Pragma("unroll") for (int cc_ = 0; cc_ < (N); ++cc_) {           \
    float4 qv_ = xs4[pk];                                           \
    float dx_ = kx - qv_.x, dy_ = ky - qv_.y, dz_ = kz - qv_.z;     \
    float dd_ = dx_ * dx_ + dy_ * dy_ + dz_ * dz_;                  \
    ins_exact(ks0, ks1, ks2, ki0, ki1, ki2, dd_, pk);               \
    pk += 8;                                                        \
  }

  const int b_off = (wave * 64 + m) * 32 + q * 8;
  const int a_base = m * 32 + q * 8;

  for (int st = 0; st < 2; ++st) {
    const int row0t = row0 + st * 32;

    // ---- build: As[t][row][kk], elem off = t*1024 + rl*32 + kk ----
#pragma unroll 4
    for (int it = 0; it < 8; ++it) {
      int rl = wave * 8 + it;
      int row = row0t + rl;
      int i0 = idxL[rl * 3 + 0], i1 = idxL[rl * 3 + 1], i2 = idxL[rl * 3 + 2];
      float w0 = wL[rl * 3 + 0], w1 = wL[rl * 3 + 1], w2 = wL[rl * 3 + 2];

      const float4* f0 = (const float4*)(feat2 + ((size_t)b * N2_ + i0) * C2_);
      const float4* f1 = (const float4*)(feat2 + ((size_t)b * N2_ + i1) * C2_);
      const float4* f2 = (const float4*)(feat2 + ((size_t)b * N2_ + i2) * C2_);
      float4 a = f0[lane];
      float4 c = f1[lane];
      float4 d = f2[lane];
      float vx = w0 * a.x + w1 * c.x + w2 * d.x;
      float vy = w0 * a.y + w1 * c.y + w2 * d.y;
      float vz = w0 * a.z + w1 * c.z + w2 * d.z;
      float vw = w0 * a.w + w1 * c.w + w2 * d.w;
      uint_t lo = (uint_t)f2bf(vx) | ((uint_t)f2bf(vy) << 16);
      uint_t hi = (uint_t)f2bf(vz) | ((uint_t)f2bf(vw) << 16);
      int e = (lane >> 3) * 1024 + rl * 32 + ((4 * lane) & 31);
      *(uint2*)&As[e] = make_uint2(lo, hi);

      float2 t1 = ((const float2*)(feat1 + (size_t)row * C1_))[lane];
      uint_t pkk = (uint_t)f2bf(t1.x) | ((uint_t)f2bf(t1.y) << 16);
      int e1 = (8 + (lane >> 4)) * 1024 + rl * 32 + ((2 * lane) & 31);
      *(uint_t*)&As[e1] = pkk;
    }
    __syncthreads();

    // ---- GEMM1: K = 384, acc[2][4]; knn chunks interleaved when st==0 ----
    floatx4 acc[2][4];
#pragma unroll
    for (int i = 0; i < 2; ++i)
#pragma unroll
      for (int j = 0; j < 4; ++j) acc[i][j] = (floatx4)0.0f;

    {
      bf16x8 bf0[4], bf1[4], af[2];
#pragma unroll
      for (int j = 0; j < 4; ++j)
        bf0[j] = *(const bf16x8*)(W1s + b_off + j * 512);
#pragma unroll
      for (int t = 0; t < 12; t += 2) {
#pragma unroll
        for (int j = 0; j < 4; ++j)
          bf1[j] = *(const bf16x8*)(W1s + (size_t)(t + 1) * 8192 + b_off + j * 512);
#pragma unroll
        for (int i = 0; i < 2; ++i)
          af[i] = *(const bf16x8*)&As[t * 1024 + a_base + i * 512];
#pragma unroll
        for (int i = 0; i < 2; ++i)
#pragma unroll
          for (int j = 0; j < 4; ++j)
            acc[i][j] = __builtin_amdgcn_mfma_f32_16x16x32_bf16(af[i], bf0[j],
                                                                acc[i][j], 0, 0, 0);
        if (st == 0) { KNN_CHUNK(6); }
        if (t + 2 < 12) {
#pragma unroll
          for (int j = 0; j < 4; ++j)
            bf0[j] = *(const bf16x8*)(W1s + (size_t)(t + 2) * 8192 + b_off + j * 512);
        }
#pragma unroll
        for (int i = 0; i < 2; ++i)
          af[i] = *(const bf16x8*)&As[(t + 1) * 1024 + a_base + i * 512];
#pragma unroll
        for (int i = 0; i < 2; ++i)
#pragma unroll
          for (int j = 0; j < 4; ++j)
            acc[i][j] = __builtin_amdgcn_mfma_f32_16x16x32_bf16(af[i], bf1[j],
                                                                acc[i][j], 0, 0, 0);
        if (st == 0) { KNN_CHUNK(6); }
      }
    }
    __syncthreads();  // all As reads done before HS overwrites the region

    // ---- epilogue1: bias + relu -> bf16 HS (aliases As front 16 KB) ----
    ushort_t* HS = As;  // 32 x 256 = 8192 elems
#pragma unroll
    for (int j = 0; j < 4; ++j) {
      int col = wave * 64 + j * 16 + m;
      float bv = b1[col];
      int cb = (col >> 3) & 3;
      int tb = (col >> 5) * 1024 + (col & 7);
#pragma unroll
      for (int i = 0; i < 2; ++i)
#pragma unroll
        for (int r = 0; r < 4; ++r) {
          int row = i * 16 + q * 4 + r;
          float v = acc[i][j][r] + bv;
          v = v > 0.0f ? v : 0.0f;
          int ch = cb ^ ((row >> 2) & 3);
          HS[tb + row * 32 + ch * 8] = f2bf(v);
        }
    }
    __syncthreads();

    // ---- GEMM2: K = 256; knn chunks interleaved when st==0 ----
    floatx4 acc2[2][4];
#pragma unroll
    for (int i = 0; i < 2; ++i)
#pragma unroll
      for (int j = 0; j < 4; ++j) acc2[i][j] = (floatx4)0.0f;

    {
      bf16x8 bf0[4], bf1[4], af[2];
#pragma unroll
      for (int j = 0; j < 4; ++j)
        bf0[j] = *(const bf16x8*)(W2s + b_off + j * 512);
#pragma unroll
      for (int t = 0; t < 8; t += 2) {
#pragma unroll
        for (int j = 0; j < 4; ++j)
          bf1[j] = *(const bf16x8*)(W2s + (size_t)(t + 1) * 8192 + b_off + j * 512);
#pragma unroll
        for (int i = 0; i < 2; ++i) {
          int row = m + 16 * i;
          int ch = q ^ ((row >> 2) & 3);
          af[i] = *(const bf16x8*)&HS[t * 1024 + row * 32 + ch * 8];
        }
#pragma unroll
        for (int i = 0; i < 2; ++i)
#pragma unroll
          for (int j = 0; j < 4; ++j)
            acc2[i][j] = __builtin_amdgcn_mfma_f32_16x16x32_bf16(af[i], bf0[j],
                                                                 acc2[i][j], 0, 0, 0);
        if (st == 0) { KNN_CHUNK(6); }
        if (t + 2 < 8) {
#pragma unroll
          for (int j = 0; j < 4; ++j)
            bf0[j] = *(const bf16x8*)(W2s + (size_t)(t + 2) * 8192 + b_off + j * 512);
        }
#pragma unroll
        for (int i = 0; i < 2; ++i) {
          int row = m + 16 * i;
          int ch = q ^ ((row >> 2) & 3);
          af[i] = *(const bf16x8*)&HS[(t + 1) * 1024 + row * 32 + ch * 8];
        }
#pragma unroll
        for (int i = 0; i < 2; ++i)
#pragma unroll
          for (int j = 0; j < 4; ++j)
            acc2[i][j] = __builtin_amdgcn_mfma_f32_16x16x32_bf16(af[i], bf1[j],
                                                                 acc2[i][j], 0, 0, 0);
        if (st == 0) { KNN_CHUNK(6); }
      }
    }

    // ---- epilogue2: bias + relu -> fp32 out ----
#pragma unroll
    for (int j = 0; j < 4; ++j) {
      int col = wave * 64 + j * 16 + m;
      float bv = b2[col];
#pragma unroll
      for (int i = 0; i < 2; ++i)
#pragma unroll
        for (int r = 0; r < 4; ++r) {
          int row = i * 16 + q * 4 + r;
          float v = acc2[i][j][r] + bv;
          v = v > 0.0f ? v : 0.0f;
          out[(size_t)(row0t + row) * DOUT_ + col] = v;
        }
    }

    // ---- knn(tile1) tail: leftover 8 candidates + merge + writeback ----
    if (st == 0) {
      KNN_CHUNK(8);  // 120 in-gemm + 8 = 128 = full scan
#pragma unroll
      for (int mm = 1; mm <= 4; mm <<= 1) {
        float e0 = __shfl_xor(ks0, mm), e1 = __shfl_xor(ks1, mm), e2 = __shfl_xor(ks2, mm);
        int j0 = __shfl_xor(ki0, mm), j1 = __shfl_xor(ki1, mm), j2 = __shfl_xor(ki2, mm);
        ins_merge(ks0, ks1, ks2, ki0, ki1, ki2, e0, j0);
        ins_merge(ks0, ks1, ks2, ki0, ki1, ki2, e1, j1);
        ins_merge(ks0, ks1, ks2, ki0, ki1, ki2, e2, j2);
      }
      if (subk == 0) {
        float r0 = 1.0f / fmaxf(ks0, 1e-10f);
        float r1 = 1.0f / fmaxf(ks1, 1e-10f);
        float r2 = 1.0f / fmaxf(ks2, 1e-10f);
        float s = 1.0f / (r0 + r1 + r2);
        idxL[gk * 3 + 0] = ki0; idxL[gk * 3 + 1] = ki1; idxL[gk * 3 + 2] = ki2;
        wL[gk * 3 + 0] = r0 * s; wL[gk * 3 + 1] = r1 * s; wL[gk * 3 + 2] = r2 * s;
      }
    }
    // (a) HS reads done before next build overwrites As;
    // (b) idxL/wL(tile1) visible to next build.
    __syncthreads();
  }
#undef KNN_CHUNK
}

// ---------------- workspace layout ----------------

constexpr size_t OFF_W1S = 0;                  // 256*384*2 = 196608
constexpr size_t OFF_W2S = OFF_W1S + 196608;   // 256*256*2 = 131072
constexpr size_t WS_TOTAL = OFF_W2S + 131072;  // 320 KB

extern "C" void kernel_launch(void* const* d_in, const int* in_sizes, int n_in,
                              void* d_out, int out_size, void* d_ws, size_t ws_size,
                              hipStream_t stream) {
  const float* xyz1 = (const float*)d_in[0];
  const float* feat1 = (const float*)d_in[1];
  const float* xyz2 = (const float*)d_in[2];
  const float* feat2 = (const float*)d_in[3];
  const float* W1 = (const float*)d_in[4];
  const float* b1 = (const float*)d_in[5];
  const float* W2 = (const float*)d_in[6];
  const float* b2 = (const float*)d_in[7];

  if (ws_size < WS_TOTAL) return;

  char* ws = (char*)d_ws;
  ushort_t* W1s = (ushort_t*)(ws + OFF_W1S);
  ushort_t* W2s = (ushort_t*)(ws + OFF_W2S);

  prep_kernel<<<384, 256, 0, stream>>>(W1, W2, W1s, W2s);
  fused_kernel<<<M_ / 64, 256, 0, stream>>>(xyz1, xyz2, feat1, feat2, W1s, b1,
                                            W2s, b2, (float*)d_out);
}

// Round 10
// 325.438 us; speedup vs baseline: 1.1296x; 1.1296x over previous
//
#include <hip/hip_runtime.h>
#include <cstdint>
#include <cstddef>

typedef unsigned short ushort_t;
typedef unsigned int uint_t;

typedef __bf16 bf16x8 __attribute__((ext_vector_type(8)));
typedef float floatx4 __attribute__((ext_vector_type(4)));

#define B_ 16
#define N1_ 4096
#define N2_ 1024
#define C1_ 128
#define C2_ 256
#define DIN_ 384
#define DOUT_ 256
#define M_ (B_ * N1_)  // 65536
#define TILES_ 4       // 32-row tiles per block -> 128 rows/block, grid 512

// ---------------- helpers ----------------

__device__ __forceinline__ ushort_t f2bf(float f) {
  unsigned int u = __builtin_bit_cast(unsigned int, f);
  u = (u + 0x7fffu + ((u >> 16) & 1u)) >> 16;  // RNE
  return (ushort_t)u;
}

// ---------------- kernel P: weight swizzle + bf16 convert ----------------
// W1s[t][n][kk] = bf16(W1[t*32+kk][n]), t=0..11, n=0..255, kk=0..31

__global__ __launch_bounds__(256) void prep_kernel(
    const float* __restrict__ W1, const float* __restrict__ W2,
    ushort_t* __restrict__ W1s, ushort_t* __restrict__ W2s) {
  int e = blockIdx.x * 256 + threadIdx.x;
  if (e < DOUT_ * DIN_) {  // 98304
    int kk = e & 31, n = (e >> 5) & 255, t = e >> 13;
    W1s[e] = f2bf(W1[(size_t)(t * 32 + kk) * DOUT_ + n]);
  }
  if (e < DOUT_ * DOUT_) {  // 65536
    int kk = e & 31, n = (e >> 5) & 255, t = e >> 13;
    W2s[e] = f2bf(W2[(size_t)(t * 32 + kk) * DOUT_ + n]);
  }
}

// ---------------- knn primitives (verbatim from verified kernels) ----------

__device__ __forceinline__ void ins_exact(float& s0, float& s1, float& s2,
                                          int& i0, int& i1, int& i2,
                                          float d, int p) {
  float ns2 = __builtin_amdgcn_fmed3f(d, s1, s2);
  float ns1 = __builtin_amdgcn_fmed3f(d, s0, s1);
  float ns0 = fminf(d, s0);
  bool c0 = d < s0, c1 = d < s1, c2 = d < s2;
  i2 = c1 ? i1 : (c2 ? p : i2);
  i1 = c0 ? i0 : (c1 ? p : i1);
  i0 = c0 ? p : i0;
  s0 = ns0; s1 = ns1; s2 = ns2;
}

__device__ __forceinline__ void ins_merge(float& s0, float& s1, float& s2,
                                          int& i0, int& i1, int& i2,
                                          float e, int j) {
  bool t0 = (e < s0) || (e == s0 && j < i0);
  bool t1 = (e < s1) || (e == s1 && j < i1);
  bool t2 = (e < s2) || (e == s2 && j < i2);
  s2 = t1 ? s1 : (t2 ? e : s2);
  i2 = t1 ? i1 : (t2 ? j : i2);
  s1 = t0 ? s0 : (t1 ? e : s1);
  i1 = t0 ? i0 : (t1 ? j : i1);
  s0 = t0 ? e : s0;
  i0 = t0 ? j : i0;
}

// ---------------- fused, wave-specialized producer/consumer ----------------
// 512 threads = 8 waves. Waves 0-3 (GEMM crew): R8-verbatim 32-row
// build/GEMM1/epi1/GEMM2/epi2. Waves 4-7 (knn crew): R6-verbatim dual-chain
// ILP2 scan for tile t+1 (ILP2 because crew = 2 waves/SIMD — R5 lesson),
// chunked 22/22/10/10 iterations between the GEMM crew's 4 existing
// barriers. idx/w double-buffered in LDS. 4 tiles/block (prologue knn
// exposed once per 4 tiles). Disjoint register files (no thread runs both
// workloads) -> the R9 spill mode is structurally excluded; disjoint issue
// pipes (VALU vs MFMA/VMEM) co-schedule at max, not sum (m114).

__global__ __launch_bounds__(512, 4) void fused_kernel(
    const float* __restrict__ xyz1, const float* __restrict__ xyz2,
    const float* __restrict__ feat1, const float* __restrict__ feat2,
    const ushort_t* __restrict__ W1s, const float* __restrict__ b1,
    const ushort_t* __restrict__ W2s, const float* __restrict__ b2,
    float* __restrict__ out) {
  __shared__ __align__(16) float4 xs4[N2_];        // 16 KB, live whole block
  __shared__ __align__(16) ushort_t As[32 * 384];  // 24 KB; HS aliases front
  __shared__ int idxL[2][32 * 3];                  // double-buffered
  __shared__ float wL[2][32 * 3];

  const int tid = threadIdx.x;
  const int row0 = blockIdx.x * (TILES_ * 32);
  const int b = row0 >> 12;  // 128-row blocks never straddle a batch

  // ---- stage xyz2 batch slice (all 512 threads) ----
  for (int i = tid; i < N2_; i += 512) {
    const float* s = xyz2 + ((size_t)b * N2_ + i) * 3;
    xs4[i] = make_float4(s[0], s[1], s[2], 0.0f);
  }
  __syncthreads();

  const bool knnCrew = (tid >= 256);
  const int kt = tid & 255;
  const int gk = kt >> 3;   // knn: row within tile
  const int subk = kt & 7;  // knn: candidate sub-slice

  // GEMM-crew ids (valid when tid < 256)
  const int wave = tid >> 6;
  const int lane = tid & 63;
  const int m = lane & 15;
  const int q = lane >> 4;
  const int b_off = (wave * 64 + m) * 32 + q * 8;
  const int a_base = m * 32 + q * 8;

  // knn persistent state (live only on knn-crew waves)
  float kx, ky, kz;
  float as0, as1, as2, bs0, bs1, bs2;
  int ai0, ai1, ai2, bi0, bi1, bi2;
  int pA, pB;

#define KNN_INIT(ROW)                                   \
  do {                                                  \
    const float* p1_ = xyz1 + (size_t)(ROW) * 3;        \
    kx = p1_[0]; ky = p1_[1]; kz = p1_[2];              \
    as0 = 3.0e38f; as1 = 3.0e38f; as2 = 3.0e38f;        \
    bs0 = 3.0e38f; bs1 = 3.0e38f; bs2 = 3.0e38f;        \
    ai0 = 0; ai1 = 0; ai2 = 0;                          \
    bi0 = 0; bi1 = 0; bi2 = 0;                          \
    pA = subk; pB = subk + 8;                           \
  } while (0)

#define KNN_ITERS(N)                                              \
  do {                                                            \
    _Pragma("unroll 2") for (int ii_ = 0; ii_ < (N); ++ii_) {     \
      float4 qa_ = xs4[pA];                                       \
      float4 qb_ = xs4[pB];                                       \
      {                                                           \
        float dx_ = kx - qa_.x, dy_ = ky - qa_.y, dz_ = kz - qa_.z; \
        float d_ = dx_ * dx_ + dy_ * dy_ + dz_ * dz_;             \
        ins_exact(as0, as1, as2, ai0, ai1, ai2, d_, pA);          \
      }                                                           \
      {                                                           \
        float dx_ = kx - qb_.x, dy_ = ky - qb_.y, dz_ = kz - qb_.z; \
        float d_ = dx_ * dx_ + dy_ * dy_ + dz_ * dz_;             \
        ins_exact(bs0, bs1, bs2, bi0, bi1, bi2, d_, pB);          \
      }                                                           \
      pA += 16; pB += 16;                                         \
    }                                                             \
  } while (0)

#define KNN_FINISH(BUF)                                                     \
  do {                                                                      \
    ins_merge(as0, as1, as2, ai0, ai1, ai2, bs0, bi0);                      \
    ins_merge(as0, as1, as2, ai0, ai1, ai2, bs1, bi1);                      \
    ins_merge(as0, as1, as2, ai0, ai1, ai2, bs2, bi2);                      \
    _Pragma("unroll") for (int mm_ = 1; mm_ <= 4; mm_ <<= 1) {              \
      float e0_ = __shfl_xor(as0, mm_), e1_ = __shfl_xor(as1, mm_),         \
            e2_ = __shfl_xor(as2, mm_);                                     \
      int j0_ = __shfl_xor(ai0, mm_), j1_ = __shfl_xor(ai1, mm_),           \
          j2_ = __shfl_xor(ai2, mm_);                                       \
      ins_merge(as0, as1, as2, ai0, ai1, ai2, e0_, j0_);                    \
      ins_merge(as0, as1, as2, ai0, ai1, ai2, e1_, j1_);                    \
      ins_merge(as0, as1, as2, ai0, ai1, ai2, e2_, j2_);                    \
    }                                                                       \
    if (subk == 0) {                                                        \
      float r0_ = 1.0f / fmaxf(as0, 1e-10f);                                \
      float r1_ = 1.0f / fmaxf(as1, 1e-10f);                                \
      float r2_ = 1.0f / fmaxf(as2, 1e-10f);                                \
      float s_ = 1.0f / (r0_ + r1_ + r2_);                                  \
      idxL[BUF][gk * 3 + 0] = ai0;                                          \
      idxL[BUF][gk * 3 + 1] = ai1;                                          \
      idxL[BUF][gk * 3 + 2] = ai2;                                          \
      wL[BUF][gk * 3 + 0] = r0_ * s_;                                       \
      wL[BUF][gk * 3 + 1] = r1_ * s_;                                       \
      wL[BUF][gk * 3 + 2] = r2_ * s_;                                       \
    }                                                                       \
  } while (0)

  // ---- prologue: knn(tile0) by knn crew (GEMM crew waits) ----
  if (knnCrew) {
    KNN_INIT(row0 + gk);
    KNN_ITERS(64);
    KNN_FINISH(0);
  }
  __syncthreads();

  for (int t = 0; t < TILES_; ++t) {
    const int cur = t & 1;
    const int row0t = row0 + t * 32;
    const bool haveNext = (t + 1 < TILES_);

    // ---- Phase 1: build(tile t) | knn(t+1) iters 0..21 ----
    if (!knnCrew) {
#pragma unroll 4
      for (int it = 0; it < 8; ++it) {
        int rl = wave * 8 + it;
        int row = row0t + rl;
        int i0 = idxL[cur][rl * 3 + 0], i1 = idxL[cur][rl * 3 + 1],
            i2 = idxL[cur][rl * 3 + 2];
        float w0 = wL[cur][rl * 3 + 0], w1 = wL[cur][rl * 3 + 1],
              w2 = wL[cur][rl * 3 + 2];

        const float4* f0 = (const float4*)(feat2 + ((size_t)b * N2_ + i0) * C2_);
        const float4* f1 = (const float4*)(feat2 + ((size_t)b * N2_ + i1) * C2_);
        const float4* f2 = (const float4*)(feat2 + ((size_t)b * N2_ + i2) * C2_);
        float4 a = f0[lane];
        float4 c = f1[lane];
        float4 d = f2[lane];
        float vx = w0 * a.x + w1 * c.x + w2 * d.x;
        float vy = w0 * a.y + w1 * c.y + w2 * d.y;
        float vz = w0 * a.z + w1 * c.z + w2 * d.z;
        float vw = w0 * a.w + w1 * c.w + w2 * d.w;
        uint_t lo = (uint_t)f2bf(vx) | ((uint_t)f2bf(vy) << 16);
        uint_t hi = (uint_t)f2bf(vz) | ((uint_t)f2bf(vw) << 16);
        int e = (lane >> 3) * 1024 + rl * 32 + ((4 * lane) & 31);
        *(uint2*)&As[e] = make_uint2(lo, hi);

        float2 t1 = ((const float2*)(feat1 + (size_t)row * C1_))[lane];
        uint_t pkk = (uint_t)f2bf(t1.x) | ((uint_t)f2bf(t1.y) << 16);
        int e1 = (8 + (lane >> 4)) * 1024 + rl * 32 + ((2 * lane) & 31);
        *(uint_t*)&As[e1] = pkk;
      }
    } else if (haveNext) {
      KNN_INIT(row0 + (t + 1) * 32 + gk);
      KNN_ITERS(22);
    }
    __syncthreads();  // As ready

    // ---- Phase 2: GEMM1 (K=384) | knn iters 22..43 ----
    floatx4 acc[2][4];
    if (!knnCrew) {
#pragma unroll
      for (int i = 0; i < 2; ++i)
#pragma unroll
        for (int j = 0; j < 4; ++j) acc[i][j] = (floatx4)0.0f;

      bf16x8 bf0[4], bf1[4], af[2];
#pragma unroll
      for (int j = 0; j < 4; ++j)
        bf0[j] = *(const bf16x8*)(W1s + b_off + j * 512);
#pragma unroll
      for (int tt = 0; tt < 12; tt += 2) {
#pragma unroll
        for (int j = 0; j < 4; ++j)
          bf1[j] = *(const bf16x8*)(W1s + (size_t)(tt + 1) * 8192 + b_off + j * 512);
#pragma unroll
        for (int i = 0; i < 2; ++i)
          af[i] = *(const bf16x8*)&As[tt * 1024 + a_base + i * 512];
#pragma unroll
        for (int i = 0; i < 2; ++i)
#pragma unroll
          for (int j = 0; j < 4; ++j)
            acc[i][j] = __builtin_amdgcn_mfma_f32_16x16x32_bf16(af[i], bf0[j],
                                                                acc[i][j], 0, 0, 0);
        if (tt + 2 < 12) {
#pragma unroll
          for (int j = 0; j < 4; ++j)
            bf0[j] = *(const bf16x8*)(W1s + (size_t)(tt + 2) * 8192 + b_off + j * 512);
        }
#pragma unroll
        for (int i = 0; i < 2; ++i)
          af[i] = *(const bf16x8*)&As[(tt + 1) * 1024 + a_base + i * 512];
#pragma unroll
        for (int i = 0; i < 2; ++i)
#pragma unroll
          for (int j = 0; j < 4; ++j)
            acc[i][j] = __builtin_amdgcn_mfma_f32_16x16x32_bf16(af[i], bf1[j],
                                                                acc[i][j], 0, 0, 0);
      }
    } else if (haveNext) {
      KNN_ITERS(22);
    }
    __syncthreads();  // As reads done before HS overwrites

    // ---- Phase 3: epilogue1 -> HS | knn iters 44..53 ----
    ushort_t* HS = As;
    if (!knnCrew) {
#pragma unroll
      for (int j = 0; j < 4; ++j) {
        int col = wave * 64 + j * 16 + m;
        float bv = b1[col];
        int cb = (col >> 3) & 3;
        int tb = (col >> 5) * 1024 + (col & 7);
#pragma unroll
        for (int i = 0; i < 2; ++i)
#pragma unroll
          for (int r = 0; r < 4; ++r) {
            int row = i * 16 + q * 4 + r;
            float v = acc[i][j][r] + bv;
            v = v > 0.0f ? v : 0.0f;
            int ch = cb ^ ((row >> 2) & 3);
            HS[tb + row * 32 + ch * 8] = f2bf(v);
          }
      }
    } else if (haveNext) {
      KNN_ITERS(10);
    }
    __syncthreads();  // HS ready

    // ---- Phase 4: GEMM2 + epilogue2 | knn iters 54..63 + finish ----
    if (!knnCrew) {
      floatx4 acc2[2][4];
#pragma unroll
      for (int i = 0; i < 2; ++i)
#pragma unroll
        for (int j = 0; j < 4; ++j) acc2[i][j] = (floatx4)0.0f;

      bf16x8 bf0[4], bf1[4], af[2];
#pragma unroll
      for (int j = 0; j < 4; ++j)
        bf0[j] = *(const bf16x8*)(W2s + b_off + j * 512);
#pragma unroll
      for (int tt = 0; tt < 8; tt += 2) {
#pragma unroll
        for (int j = 0; j < 4; ++j)
          bf1[j] = *(const bf16x8*)(W2s + (size_t)(tt + 1) * 8192 + b_off + j * 512);
#pragma unroll
        for (int i = 0; i < 2; ++i) {
          int row = m + 16 * i;
          int ch = q ^ ((row >> 2) & 3);
          af[i] = *(const bf16x8*)&HS[tt * 1024 + row * 32 + ch * 8];
        }
#pragma unroll
        for (int i = 0; i < 2; ++i)
#pragma unroll
          for (int j = 0; j < 4; ++j)
            acc2[i][j] = __builtin_amdgcn_mfma_f32_16x16x32_bf16(af[i], bf0[j],
                                                                 acc2[i][j], 0, 0, 0);
        if (tt + 2 < 8) {
#pragma unroll
          for (int j = 0; j < 4; ++j)
            bf0[j] = *(const bf16x8*)(W2s + (size_t)(tt + 2) * 8192 + b_off + j * 512);
        }
#pragma unroll
        for (int i = 0; i < 2; ++i) {
          int row = m + 16 * i;
          int ch = q ^ ((row >> 2) & 3);
          af[i] = *(const bf16x8*)&HS[(tt + 1) * 1024 + row * 32 + ch * 8];
        }
#pragma unroll
        for (int i = 0; i < 2; ++i)
#pragma unroll
          for (int j = 0; j < 4; ++j)
            acc2[i][j] = __builtin_amdgcn_mfma_f32_16x16x32_bf16(af[i], bf1[j],
                                                                 acc2[i][j], 0, 0, 0);
      }

#pragma unroll
      for (int j = 0; j < 4; ++j) {
        int col = wave * 64 + j * 16 + m;
        float bv = b2[col];
#pragma unroll
        for (int i = 0; i < 2; ++i)
#pragma unroll
          for (int r = 0; r < 4; ++r) {
            int row = i * 16 + q * 4 + r;
            float v = acc2[i][j][r] + bv;
            v = v > 0.0f ? v : 0.0f;
            out[(size_t)(row0t + row) * DOUT_ + col] = v;
          }
      }
    } else if (haveNext) {
      KNN_ITERS(10);     // 22+22+10+10 = 64 iters = 128 candidates
      KNN_FINISH(cur ^ 1);
    }
    // HS reads done before next build overwrites As; idxL[cur^1] visible
    __syncthreads();
  }
#undef KNN_INIT
#undef KNN_ITERS
#undef KNN_FINISH
}

// ---------------- workspace layout ----------------

constexpr size_t OFF_W1S = 0;                  // 256*384*2 = 196608
constexpr size_t OFF_W2S = OFF_W1S + 196608;   // 256*256*2 = 131072
constexpr size_t WS_TOTAL = OFF_W2S + 131072;  // 320 KB

extern "C" void kernel_launch(void* const* d_in, const int* in_sizes, int n_in,
                              void* d_out, int out_size, void* d_ws, size_t ws_size,
                              hipStream_t stream) {
  const float* xyz1 = (const float*)d_in[0];
  const float* feat1 = (const float*)d_in[1];
  const float* xyz2 = (const float*)d_in[2];
  const float* feat2 = (const float*)d_in[3];
  const float* W1 = (const float*)d_in[4];
  const float* b1 = (const float*)d_in[5];
  const float* W2 = (const float*)d_in[6];
  const float* b2 = (const float*)d_in[7];

  if (ws_size < WS_TOTAL) return;

  char* ws = (char*)d_ws;
  ushort_t* W1s = (ushort_t*)(ws + OFF_W1S);
  ushort_t* W2s = (ushort_t*)(ws + OFF_W2S);

  prep_kernel<<<384, 256, 0, stream>>>(W1, W2, W1s, W2s);
  fused_kernel<<<M_ / (TILES_ * 32), 512, 0, stream>>>(
      xyz1, xyz2, feat1, feat2, W1s, b1, W2s, b2, (float*)d_out);
}

// Round 11
// 179.857 us; speedup vs baseline: 2.0440x; 1.8094x over previous
//
#include <hip/hip_runtime.h>
#include <cstdint>
#include <cstddef>

typedef unsigned short ushort_t;
typedef unsigned int uint_t;

typedef __bf16 bf16x8 __attribute__((ext_vector_type(8)));
typedef float floatx4 __attribute__((ext_vector_type(4)));

#define B_ 16
#define N1_ 4096
#define N2_ 1024
#define C1_ 128
#define C2_ 256
#define DIN_ 384
#define DOUT_ 256
#define M_ (B_ * N1_)  // 65536

// ---------------- helpers ----------------

__device__ __forceinline__ ushort_t f2bf(float f) {
  unsigned int u = __builtin_bit_cast(unsigned int, f);
  u = (u + 0x7fffu + ((u >> 16) & 1u)) >> 16;  // RNE
  return (ushort_t)u;
}

// ---------------- kernel P: weight swizzle + bf16 convert ----------------
// W1s[t][n][kk] = bf16(W1[t*32+kk][n]), t=0..11, n=0..255, kk=0..31

__global__ __launch_bounds__(256) void prep_kernel(
    const float* __restrict__ W1, const float* __restrict__ W2,
    ushort_t* __restrict__ W1s, ushort_t* __restrict__ W2s) {
  int e = blockIdx.x * 256 + threadIdx.x;
  if (e < DOUT_ * DIN_) {  // 98304
    int kk = e & 31, n = (e >> 5) & 255, t = e >> 13;
    W1s[e] = f2bf(W1[(size_t)(t * 32 + kk) * DOUT_ + n]);
  }
  if (e < DOUT_ * DOUT_) {  // 65536
    int kk = e & 31, n = (e >> 5) & 255, t = e >> 13;
    W2s[e] = f2bf(W2[(size_t)(t * 32 + kk) * DOUT_ + n]);
  }
}

// ---------------- knn primitives (verbatim from verified kernels) ----------

__device__ __forceinline__ void ins_exact(float& s0, float& s1, float& s2,
                                          int& i0, int& i1, int& i2,
                                          float d, int p) {
  float ns2 = __builtin_amdgcn_fmed3f(d, s1, s2);
  float ns1 = __builtin_amdgcn_fmed3f(d, s0, s1);
  float ns0 = fminf(d, s0);
  bool c0 = d < s0, c1 = d < s1, c2 = d < s2;
  i2 = c1 ? i1 : (c2 ? p : i2);
  i1 = c0 ? i0 : (c1 ? p : i1);
  i0 = c0 ? p : i0;
  s0 = ns0; s1 = ns1; s2 = ns2;
}

__device__ __forceinline__ void ins_merge(float& s0, float& s1, float& s2,
                                          int& i0, int& i1, int& i2,
                                          float e, int j) {
  bool t0 = (e < s0) || (e == s0 && j < i0);
  bool t1 = (e < s1) || (e == s1 && j < i1);
  bool t2 = (e < s2) || (e == s2 && j < i2);
  s2 = t1 ? s1 : (t2 ? e : s2);
  i2 = t1 ? i1 : (t2 ? j : i2);
  s1 = t0 ? s0 : (t1 ? e : s1);
  i1 = t0 ? i0 : (t1 ? j : i1);
  s0 = t0 ? e : s0;
  i0 = t0 ? j : i0;
}

// ---------------- fully fused: knn + build + GEMM1 + GEMM2 ----------------
// R8 structure (182 us verified: 32 rows/block, 2048 blocks, 24.75 KB LDS,
// ~4 blocks/CU) with ONE change: the knn phase uses TWO interleaved
// candidate chains per thread (p = sub and p = sub+8, step 16; 64 iters
// instead of 128), folded with the R6-verified index-tiebreak merge.
// Rationale: standalone knn at 8 waves/SIMD is issue-bound (ILP2 neutral,
// R6), but here the knn phase runs at ~4 waves/SIMD sharing issue with
// GEMM-phase waves of other blocks -> latency-exposed; halving the
// dependent-chain length halves the exposed phase.
// R9/R10 lesson encoded: NO knn work inside or alongside the GEMM
// instruction stream (register-union spills); phases stay sequential
// within a block, overlap comes from block-level drift only.

__global__ __launch_bounds__(256, 2) void fused_kernel(
    const float* __restrict__ xyz1, const float* __restrict__ xyz2,
    const float* __restrict__ feat1, const float* __restrict__ feat2,
    const ushort_t* __restrict__ W1s, const float* __restrict__ b1,
    const ushort_t* __restrict__ W2s, const float* __restrict__ b2,
    float* __restrict__ out) {
  __shared__ __align__(16) ushort_t As[32 * 384];  // 24 KB; xs4 (16 KB) + HS (16 KB) alias it
  __shared__ int idxL[32 * 3];
  __shared__ float wL[32 * 3];

  const int tid = threadIdx.x;
  const int wave = tid >> 6;
  const int lane = tid & 63;
  const int m = lane & 15;
  const int q = lane >> 4;
  const int row0 = blockIdx.x * 32;
  const int b = row0 >> 12;

  // ---- stage xyz2 batch slice into LDS (aliases As front 16 KB) ----
  float4* xs4 = (float4*)As;
  {
    const float4* p24 = (const float4*)(xyz2 + (size_t)b * (N2_ * 3));
    float4 A = p24[3 * tid + 0];
    float4 Bv = p24[3 * tid + 1];
    float4 Cv = p24[3 * tid + 2];
    xs4[4 * tid + 0] = make_float4(A.x, A.y, A.z, 0.0f);
    xs4[4 * tid + 1] = make_float4(A.w, Bv.x, Bv.y, 0.0f);
    xs4[4 * tid + 2] = make_float4(Bv.z, Bv.w, Cv.x, 0.0f);
    xs4[4 * tid + 3] = make_float4(Cv.y, Cv.z, Cv.w, 0.0f);
  }
  __syncthreads();

  // ---- knn: 32 rows, 8 subs/row, ILP2 dual chain (R6-verified merge) ----
  {
    const int g = tid >> 3;  // 0..31
    const int sub = tid & 7;
    const int row = row0 + g;
    const float* p1 = xyz1 + (size_t)row * 3;
    float x1 = p1[0], y1 = p1[1], z1 = p1[2];

    float as0 = 3.0e38f, as1 = 3.0e38f, as2 = 3.0e38f;
    float bs0 = 3.0e38f, bs1 = 3.0e38f, bs2 = 3.0e38f;
    int ai0 = 0, ai1 = 0, ai2 = 0;
    int bi0 = 0, bi1 = 0, bi2 = 0;

    int pA = sub;
    int pB = sub + 8;
#pragma unroll 8
    for (int t = 0; t < N2_ / 16; ++t) {
      float4 qa = xs4[pA];
      float4 qb = xs4[pB];
      {
        float dx = x1 - qa.x, dy = y1 - qa.y, dz = z1 - qa.z;
        float d = dx * dx + dy * dy + dz * dz;
        ins_exact(as0, as1, as2, ai0, ai1, ai2, d, pA);
      }
      {
        float dx = x1 - qb.x, dy = y1 - qb.y, dz = z1 - qb.z;
        float d = dx * dx + dy * dy + dz * dz;
        ins_exact(bs0, bs1, bs2, bi0, bi1, bi2, d, pB);
      }
      pA += 16;
      pB += 16;
    }

    // fold chain B into chain A (index-tiebreak; scan-order independent)
    ins_merge(as0, as1, as2, ai0, ai1, ai2, bs0, bi0);
    ins_merge(as0, as1, as2, ai0, ai1, ai2, bs1, bi1);
    ins_merge(as0, as1, as2, ai0, ai1, ai2, bs2, bi2);

#pragma unroll
    for (int mm = 1; mm <= 4; mm <<= 1) {
      float e0 = __shfl_xor(as0, mm), e1 = __shfl_xor(as1, mm), e2 = __shfl_xor(as2, mm);
      int j0 = __shfl_xor(ai0, mm), j1 = __shfl_xor(ai1, mm), j2 = __shfl_xor(ai2, mm);
      ins_merge(as0, as1, as2, ai0, ai1, ai2, e0, j0);
      ins_merge(as0, as1, as2, ai0, ai1, ai2, e1, j1);
      ins_merge(as0, as1, as2, ai0, ai1, ai2, e2, j2);
    }

    if (sub == 0) {
      float r0 = 1.0f / fmaxf(as0, 1e-10f);
      float r1 = 1.0f / fmaxf(as1, 1e-10f);
      float r2 = 1.0f / fmaxf(as2, 1e-10f);
      float s = 1.0f / (r0 + r1 + r2);
      idxL[g * 3 + 0] = ai0;
      idxL[g * 3 + 1] = ai1;
      idxL[g * 3 + 2] = ai2;
      wL[g * 3 + 0] = r0 * s;
      wL[g * 3 + 1] = r1 * s;
      wL[g * 3 + 2] = r2 * s;
    }
  }
  __syncthreads();  // all xs4 reads done before build overwrites As

  // ---- build phase: As[t][row][kk], elem off = t*1024 + row*32 + kk ----
#pragma unroll 4
  for (int it = 0; it < 8; ++it) {
    int rl = wave * 8 + it;
    int row = row0 + rl;
    int i0 = idxL[rl * 3 + 0], i1 = idxL[rl * 3 + 1], i2 = idxL[rl * 3 + 2];
    float w0 = wL[rl * 3 + 0], w1 = wL[rl * 3 + 1], w2 = wL[rl * 3 + 2];

    const float4* f0 = (const float4*)(feat2 + ((size_t)b * N2_ + i0) * C2_);
    const float4* f1 = (const float4*)(feat2 + ((size_t)b * N2_ + i1) * C2_);
    const float4* f2 = (const float4*)(feat2 + ((size_t)b * N2_ + i2) * C2_);
    float4 a = f0[lane];
    float4 c = f1[lane];
    float4 d = f2[lane];
    float vx = w0 * a.x + w1 * c.x + w2 * d.x;
    float vy = w0 * a.y + w1 * c.y + w2 * d.y;
    float vz = w0 * a.z + w1 * c.z + w2 * d.z;
    float vw = w0 * a.w + w1 * c.w + w2 * d.w;
    // cols 4*lane .. 4*lane+3 (never straddle a 32-col tile)
    uint_t lo = (uint_t)f2bf(vx) | ((uint_t)f2bf(vy) << 16);
    uint_t hi = (uint_t)f2bf(vz) | ((uint_t)f2bf(vw) << 16);
    int e = (lane >> 3) * 1024 + rl * 32 + ((4 * lane) & 31);
    *(uint2*)&As[e] = make_uint2(lo, hi);

    // feat1: cols 256 + 2*lane, 2*lane+1
    float2 t1 = ((const float2*)(feat1 + (size_t)row * C1_))[lane];
    uint_t pk = (uint_t)f2bf(t1.x) | ((uint_t)f2bf(t1.y) << 16);
    int e1 = (8 + (lane >> 4)) * 1024 + rl * 32 + ((2 * lane) & 31);
    *(uint_t*)&As[e1] = pk;
  }
  __syncthreads();

  // ---- GEMM1: acc[32 rows][64 cols per wave], K = 384, no barriers ----
  const int b_off = (wave * 64 + m) * 32 + q * 8;  // frag base in W1s/W2s tile
  const int a_base = m * 32 + q * 8;

  floatx4 acc[2][4];
#pragma unroll
  for (int i = 0; i < 2; ++i)
#pragma unroll
    for (int j = 0; j < 4; ++j) acc[i][j] = (floatx4)0.0f;

  {
    bf16x8 bf0[4], bf1[4], af[2];
#pragma unroll
    for (int j = 0; j < 4; ++j)
      bf0[j] = *(const bf16x8*)(W1s + b_off + j * 512);
#pragma unroll
    for (int t = 0; t < 12; t += 2) {
#pragma unroll
      for (int j = 0; j < 4; ++j)
        bf1[j] = *(const bf16x8*)(W1s + (size_t)(t + 1) * 8192 + b_off + j * 512);
#pragma unroll
      for (int i = 0; i < 2; ++i)
        af[i] = *(const bf16x8*)&As[t * 1024 + a_base + i * 512];
#pragma unroll
      for (int i = 0; i < 2; ++i)
#pragma unroll
        for (int j = 0; j < 4; ++j)
          acc[i][j] = __builtin_amdgcn_mfma_f32_16x16x32_bf16(af[i], bf0[j],
                                                              acc[i][j], 0, 0, 0);
      if (t + 2 < 12) {
#pragma unroll
        for (int j = 0; j < 4; ++j)
          bf0[j] = *(const bf16x8*)(W1s + (size_t)(t + 2) * 8192 + b_off + j * 512);
      }
#pragma unroll
      for (int i = 0; i < 2; ++i)
        af[i] = *(const bf16x8*)&As[(t + 1) * 1024 + a_base + i * 512];
#pragma unroll
      for (int i = 0; i < 2; ++i)
#pragma unroll
        for (int j = 0; j < 4; ++j)
          acc[i][j] = __builtin_amdgcn_mfma_f32_16x16x32_bf16(af[i], bf1[j],
                                                              acc[i][j], 0, 0, 0);
    }
  }
  __syncthreads();  // all As reads done before HS overwrites the region

  // ---- epilogue1: bias + relu -> bf16 HS (aliases As; XOR-chunk swizzle) ----
  ushort_t* HS = As;  // 32 x 256 = 8192 elems = 16 KB
#pragma unroll
  for (int j = 0; j < 4; ++j) {
    int col = wave * 64 + j * 16 + m;
    float bv = b1[col];
    int cb = (col >> 3) & 3;
    int tb = (col >> 5) * 1024 + (col & 7);
#pragma unroll
    for (int i = 0; i < 2; ++i)
#pragma unroll
      for (int r = 0; r < 4; ++r) {
        int row = i * 16 + q * 4 + r;
        float v = acc[i][j][r] + bv;
        v = v > 0.0f ? v : 0.0f;
        int ch = cb ^ ((row >> 2) & 3);
        HS[tb + row * 32 + ch * 8] = f2bf(v);
      }
  }
  __syncthreads();

  // ---- GEMM2: K = 256, a-frags from HS, no barriers ----
  floatx4 acc2[2][4];
#pragma unroll
  for (int i = 0; i < 2; ++i)
#pragma unroll
    for (int j = 0; j < 4; ++j) acc2[i][j] = (floatx4)0.0f;

  {
    bf16x8 bf0[4], bf1[4], af[2];
#pragma unroll
    for (int j = 0; j < 4; ++j)
      bf0[j] = *(const bf16x8*)(W2s + b_off + j * 512);
#pragma unroll
    for (int t = 0; t < 8; t += 2) {
#pragma unroll
      for (int j = 0; j < 4; ++j)
        bf1[j] = *(const bf16x8*)(W2s + (size_t)(t + 1) * 8192 + b_off + j * 512);
#pragma unroll
      for (int i = 0; i < 2; ++i) {
        int row = m + 16 * i;
        int ch = q ^ ((row >> 2) & 3);
        af[i] = *(const bf16x8*)&HS[t * 1024 + row * 32 + ch * 8];
      }
#pragma unroll
      for (int i = 0; i < 2; ++i)
#pragma unroll
        for (int j = 0; j < 4; ++j)
          acc2[i][j] = __builtin_amdgcn_mfma_f32_16x16x32_bf16(af[i], bf0[j],
                                                               acc2[i][j], 0, 0, 0);
      if (t + 2 < 8) {
#pragma unroll
        for (int j = 0; j < 4; ++j)
          bf0[j] = *(const bf16x8*)(W2s + (size_t)(t + 2) * 8192 + b_off + j * 512);
      }
#pragma unroll
      for (int i = 0; i < 2; ++i) {
        int row = m + 16 * i;
        int ch = q ^ ((row >> 2) & 3);
        af[i] = *(const bf16x8*)&HS[(t + 1) * 1024 + row * 32 + ch * 8];
      }
#pragma unroll
      for (int i = 0; i < 2; ++i)
#pragma unroll
        for (int j = 0; j < 4; ++j)
          acc2[i][j] = __builtin_amdgcn_mfma_f32_16x16x32_bf16(af[i], bf1[j],
                                                               acc2[i][j], 0, 0, 0);
    }
  }

  // ---- epilogue2: bias + relu -> fp32 out ----
#pragma unroll
  for (int j = 0; j < 4; ++j) {
    int col = wave * 64 + j * 16 + m;
    float bv = b2[col];
#pragma unroll
    for (int i = 0; i < 2; ++i)
#pragma unroll
      for (int r = 0; r < 4; ++r) {
        int row = i * 16 + q * 4 + r;
        float v = acc2[i][j][r] + bv;
        v = v > 0.0f ? v : 0.0f;
        out[(size_t)(row0 + row) * DOUT_ + col] = v;
      }
  }
}

// ---------------- workspace layout ----------------

constexpr size_t OFF_W1S = 0;                  // 256*384*2 = 196608
constexpr size_t OFF_W2S = OFF_W1S + 196608;   // 256*256*2 = 131072
constexpr size_t WS_TOTAL = OFF_W2S + 131072;  // 320 KB

extern "C" void kernel_launch(void* const* d_in, const int* in_sizes, int n_in,
                              void* d_out, int out_size, void* d_ws, size_t ws_size,
                              hipStream_t stream) {
  const float* xyz1 = (const float*)d_in[0];
  const float* feat1 = (const float*)d_in[1];
  const float* xyz2 = (const float*)d_in[2];
  const float* feat2 = (const float*)d_in[3];
  const float* W1 = (const float*)d_in[4];
  const float* b1 = (const float*)d_in[5];
  const float* W2 = (const float*)d_in[6];
  const float* b2 = (const float*)d_in[7];

  if (ws_size < WS_TOTAL) return;

  char* ws = (char*)d_ws;
  ushort_t* W1s = (ushort_t*)(ws + OFF_W1S);
  ushort_t* W2s = (ushort_t*)(ws + OFF_W2S);

  prep_kernel<<<384, 256, 0, stream>>>(W1, W2, W1s, W2s);
  fused_kernel<<<M_ / 32, 256, 0, stream>>>(xyz1, xyz2, feat1, feat2, W1s, b1,
                                            W2s, b2, (float*)d_out);
}